// Round 1
// baseline (1508.384 us; speedup 1.0000x reference)
//
#include <hip/hip_runtime.h>
#include <math.h>

#define NB 8
#define NN 4096
#define MM 2048
#define KNN_K 16
#define CIN 64
#define COUT 128
#define BN_EPS 1e-5f

// Pack (f32 key, 32-bit code) into a positive double so that f64 min/max
// compares (key, code) lexicographically. key >= 0 finite => double finite.
__device__ __forceinline__ double pack_key(float d, unsigned code) {
  return __longlong_as_double(
      (long long)(((unsigned long long)__float_as_uint(d) << 32) | code));
}
__device__ __forceinline__ unsigned unpack_code(double v) {
  return (unsigned)((unsigned long long)__double_as_longlong(v) & 0xFFFFFFFFull);
}

// numpy-exact squared distance: ((dx*dx + dy*dy) + dz*dz), no FMA contraction
__device__ __forceinline__ float sqdist_np(float dx, float dy, float dz) {
  return __fadd_rn(__fadd_rn(__fmul_rn(dx, dx), __fmul_rn(dy, dy)),
                   __fmul_rn(dz, dz));
}

// ---------------------------------------------------------------------------
// Fused kernel: blocks 0..7 = FPS (one cloud each); blocks 8..519 = GEMM tile
// (64 rows x 128 cols) + per-block BN partial sums -> global atomics.
// ---------------------------------------------------------------------------
__global__ __launch_bounds__(256) void k_fps_gemm(
    const float* __restrict__ pos, const float* __restrict__ x,
    const float* __restrict__ W, const float* __restrict__ bias,
    float* __restrict__ h, float* __restrict__ gsum,
    float* __restrict__ gsumsq, int* __restrict__ fps_idx,
    float* __restrict__ out_pos, float* __restrict__ out_batch) {
  __shared__ __align__(16) char smem_raw[50240];
  const int tid = threadIdx.x;

  if (blockIdx.x < NB) {
    // ------------------------- FPS -------------------------
    float* xs = (float*)smem_raw;
    float* ys = xs + NN;
    float* zs = ys + NN;
    double* red = (double*)(smem_raw + 49152);  // red[2][4], parity buffered
    const int b = blockIdx.x;
    const float* posc = pos + (size_t)b * NN * 3;
    for (int i = tid; i < NN; i += 256) {
      xs[i] = posc[i * 3 + 0];
      ys[i] = posc[i * 3 + 1];
      zs[i] = posc[i * 3 + 2];
    }
    __syncthreads();
    float px[16], py[16], pz[16], dmin[16];
    unsigned code[16];
#pragma unroll
    for (int s = 0; s < 16; ++s) {
      const int p = s * 256 + tid;
      px[s] = xs[p];
      py[s] = ys[p];
      pz[s] = zs[p];
      dmin[s] = __int_as_float(0x7f800000);  // +inf
      code[s] = (unsigned)(NN - 1 - p);      // max-tie -> smaller index
    }
    const int lane = tid & 63, wv = tid >> 6;
    int last = 0;
    if (tid == 0) fps_idx[b * MM] = 0;
    for (int m = 1; m < MM; ++m) {
      const float lx = xs[last], ly = ys[last], lz = zs[last];
      double best = -1.0;
#pragma unroll
      for (int s = 0; s < 16; ++s) {
        const float d = sqdist_np(px[s] - lx, py[s] - ly, pz[s] - lz);
        const float dm = fminf(dmin[s], d);
        dmin[s] = dm;
        best = fmax(best, pack_key(dm, code[s]));
      }
#pragma unroll
      for (int off = 32; off; off >>= 1)
        best = fmax(best, __shfl_xor(best, off, 64));
      const int par = (m & 1) * 4;
      if (lane == 0) red[par + wv] = best;
      __syncthreads();
      const double f = fmax(fmax(red[par + 0], red[par + 1]),
                            fmax(red[par + 2], red[par + 3]));
      last = (NN - 1) - (int)unpack_code(f);
      if (tid == 0) fps_idx[b * MM + m] = last;
    }
    __syncthreads();
    for (int m = tid; m < MM; m += 256) {
      const int p = fps_idx[b * MM + m];
      const int o = b * MM + m;
      out_pos[o * 3 + 0] = xs[p];
      out_pos[o * 3 + 1] = ys[p];
      out_pos[o * 3 + 2] = zs[p];
      out_batch[o] = (float)b;
    }
  } else {
    // ------------------- GEMM + BN partials -------------------
    float* Wl = (float*)smem_raw;    // [64][128]
    float* xl = Wl + CIN * COUT;     // [64][64]
    float* bsum = (float*)(smem_raw + 49152);
    float* bsq = bsum + COUT;
    const int bid = blockIdx.x - NB;  // 0..511
    const int r0 = bid * 64;
    for (int i = tid; i < CIN * COUT; i += 256) Wl[i] = W[i];
    for (int i = tid; i < 64 * CIN; i += 256) xl[i] = x[(size_t)r0 * CIN + i];
    if (tid < COUT) {
      bsum[tid] = 0.f;
      bsq[tid] = 0.f;
    }
    __syncthreads();
    const int cg = tid & 31, rg = tid >> 5;
    const int c = cg * 4;
    float acc[8][4];
#pragma unroll
    for (int j = 0; j < 8; ++j)
#pragma unroll
      for (int t = 0; t < 4; ++t) acc[j][t] = 0.f;
    for (int k = 0; k < CIN; ++k) {
      const float4 wk = *(const float4*)&Wl[k * COUT + c];
#pragma unroll
      for (int j = 0; j < 8; ++j) {
        const float xv = xl[(rg * 8 + j) * CIN + k];
        acc[j][0] = fmaf(xv, wk.x, acc[j][0]);
        acc[j][1] = fmaf(xv, wk.y, acc[j][1]);
        acc[j][2] = fmaf(xv, wk.z, acc[j][2]);
        acc[j][3] = fmaf(xv, wk.w, acc[j][3]);
      }
    }
    const float4 bb = *(const float4*)&bias[c];
    float s0 = 0, s1 = 0, s2 = 0, s3 = 0, q0 = 0, q1 = 0, q2 = 0, q3 = 0;
#pragma unroll
    for (int j = 0; j < 8; ++j) {
      float4 hv;
      hv.x = acc[j][0] + bb.x;
      hv.y = acc[j][1] + bb.y;
      hv.z = acc[j][2] + bb.z;
      hv.w = acc[j][3] + bb.w;
      *(float4*)&h[(size_t)(r0 + rg * 8 + j) * COUT + c] = hv;
      s0 += hv.x; s1 += hv.y; s2 += hv.z; s3 += hv.w;
      q0 += hv.x * hv.x; q1 += hv.y * hv.y;
      q2 += hv.z * hv.z; q3 += hv.w * hv.w;
    }
    atomicAdd(&bsum[c + 0], s0); atomicAdd(&bsum[c + 1], s1);
    atomicAdd(&bsum[c + 2], s2); atomicAdd(&bsum[c + 3], s3);
    atomicAdd(&bsq[c + 0], q0);  atomicAdd(&bsq[c + 1], q1);
    atomicAdd(&bsq[c + 2], q2);  atomicAdd(&bsq[c + 3], q3);
    __syncthreads();
    if (tid < COUT) {
      atomicAdd(&gsum[tid], bsum[tid]);
      atomicAdd(&gsumsq[tid], bsq[tid]);
    }
  }
}

// ---------------------------------------------------------------------------
__global__ void k_bnfin(const float* __restrict__ gsum,
                        const float* __restrict__ gsumsq,
                        const float* __restrict__ gamma,
                        const float* __restrict__ beta,
                        float* __restrict__ scale, float* __restrict__ shift) {
  const int c = threadIdx.x;
  if (c < COUT) {
    const float n = (float)(NB * NN);
    const float mu = gsum[c] / n;
    const float var = gsumsq[c] / n - mu * mu;
    const float rs = rsqrtf(var + BN_EPS);
    const float sc = rs * gamma[c];
    scale[c] = sc;
    shift[c] = beta[c] - mu * sc;
  }
}

__device__ __forceinline__ float gelu_exact(float v) {
  return 0.5f * v * (1.0f + erff(v * 0.70710678118654752f));
}

__global__ __launch_bounds__(256) void k_act(float* __restrict__ h,
                                             const float* __restrict__ scale,
                                             const float* __restrict__ shift) {
  const int g = blockIdx.x * 256 + threadIdx.x;  // float4 index
  const int c = (g & 31) * 4;
  float4* h4 = (float4*)h;
  float4 v = h4[g];
  const float4 sc = *(const float4*)&scale[c];
  const float4 sh = *(const float4*)&shift[c];
  v.x = gelu_exact(v.x * sc.x + sh.x);
  v.y = gelu_exact(v.y * sc.y + sh.y);
  v.z = gelu_exact(v.z * sc.z + sh.z);
  v.w = gelu_exact(v.w * sc.w + sh.w);
  h4[g] = v;
}

// ---------------------------------------------------------------------------
// One wave per query: exact KNN via 16x min-extraction over LDS-cached
// distances with two-level (8 groups x 8) incremental minima, then
// max-pool of the 16 neighbors' 128-ch feature rows.
// ---------------------------------------------------------------------------
__global__ __launch_bounds__(256) void k_knn(const float* __restrict__ pos,
                                             const int* __restrict__ fps_idx,
                                             const float* __restrict__ h,
                                             float* __restrict__ out_x) {
  __shared__ float dc[4][NN];  // 64 KB
  const int tid = threadIdx.x, lane = tid & 63, wv = tid >> 6;
  const int q = blockIdx.x * 4 + wv;
  const int b = q >> 11, m = q & (MM - 1);
  const int qi = fps_idx[b * MM + m];
  const float* posc = pos + (size_t)b * NN * 3;
  const float qx = posc[qi * 3 + 0], qy = posc[qi * 3 + 1],
              qz = posc[qi * 3 + 2];
  float* dcw = dc[wv];
  const double DINF = __longlong_as_double(0x7FF0000000000000LL);
  double gmin[8];
#pragma unroll
  for (int g = 0; g < 8; ++g) gmin[g] = DINF;
#pragma unroll
  for (int s = 0; s < 64; ++s) {
    const int p = s * 64 + lane;  // owner of p is lane (p % 64)
    const float d = sqdist_np(posc[p * 3 + 0] - qx, posc[p * 3 + 1] - qy,
                              posc[p * 3 + 2] - qz);
    dcw[p] = d;
    gmin[s >> 3] = fmin(gmin[s >> 3], pack_key(d, (unsigned)p));
  }
  double lmin = gmin[0];
#pragma unroll
  for (int g = 1; g < 8; ++g) lmin = fmin(lmin, gmin[g]);

  int nbr[KNN_K];
#pragma unroll
  for (int r = 0; r < KNN_K; ++r) {
    double v = lmin;
#pragma unroll
    for (int off = 32; off; off >>= 1) v = fmin(v, __shfl_xor(v, off, 64));
    const unsigned p = unpack_code(v);
    nbr[r] = (int)p;
    if (lane == (int)(p & 63)) {
      dcw[p] = __int_as_float(0x7f800000);  // remove from candidates
      const int g = (int)(p >> 9);
      double nm = DINF;
      const int base = g * 8 * 64 + lane;
#pragma unroll
      for (int j = 0; j < 8; ++j) {
        const int pp = base + j * 64;
        nm = fmin(nm, pack_key(dcw[pp], (unsigned)pp));
      }
#pragma unroll
      for (int gg = 0; gg < 8; ++gg)
        if (gg == g) gmin[gg] = nm;
      lmin = gmin[0];
#pragma unroll
      for (int gg = 1; gg < 8; ++gg) lmin = fmin(lmin, gmin[gg]);
    }
  }

  const float* hb = h + (size_t)b * NN * COUT;
  float f0 = -__int_as_float(0x7f800000), f1 = f0;
#pragma unroll
  for (int r = 0; r < KNN_K; ++r) {
    const float* row = hb + (size_t)nbr[r] * COUT;
    f0 = fmaxf(f0, row[lane]);
    f1 = fmaxf(f1, row[lane + 64]);
  }
  out_x[(size_t)q * COUT + lane] = f0;
  out_x[(size_t)q * COUT + lane + 64] = f1;
}

// ---------------------------------------------------------------------------
extern "C" void kernel_launch(void* const* d_in, const int* in_sizes, int n_in,
                              void* d_out, int out_size, void* d_ws,
                              size_t ws_size, hipStream_t stream) {
  const float* x = (const float*)d_in[0];
  const float* pos = (const float*)d_in[1];
  // d_in[2] = batch (unused; implied by layout)
  const float* W = (const float*)d_in[3];
  const float* bias = (const float*)d_in[4];
  const float* gamma = (const float*)d_in[5];
  const float* beta = (const float*)d_in[6];

  float* out_x = (float*)d_out;                          // [B*M,128]
  float* out_pos = out_x + (size_t)NB * MM * COUT;       // [B*M,3]
  float* out_batch = out_pos + (size_t)NB * MM * 3;      // [B*M]

  char* ws = (char*)d_ws;
  float* h = (float*)ws;                                 // 16 MB
  float* gsum = (float*)(ws + (size_t)16777216);
  float* gsumsq = gsum + COUT;
  float* scale = gsumsq + COUT;
  float* shift = scale + COUT;
  int* fps_idx = (int*)(shift + COUT);                   // B*M ints

  hipMemsetAsync(gsum, 0, 2 * COUT * sizeof(float), stream);
  hipLaunchKernelGGL(k_fps_gemm, dim3(NB + 512), dim3(256), 0, stream, pos, x,
                     W, bias, h, gsum, gsumsq, fps_idx, out_pos, out_batch);
  hipLaunchKernelGGL(k_bnfin, dim3(1), dim3(128), 0, stream, gsum, gsumsq,
                     gamma, beta, scale, shift);
  hipLaunchKernelGGL(k_act, dim3(4096), dim3(256), 0, stream, h, scale, shift);
  hipLaunchKernelGGL(k_knn, dim3(4096), dim3(256), 0, stream, pos, fps_idx, h,
                     out_x);
}